// Round 1
// baseline (2310.846 us; speedup 1.0000x reference)
//
#include <hip/hip_runtime.h>

#define NPn 100000
#define NSn 50000
#define PDk 1024
#define SDk 512
#define EPe 3200000
#define ESe 1600000
#define ELe 2000000

// ---------------- degree histogram ----------------
__global__ void k_deg(const int* __restrict__ dst, int E, int* __restrict__ deg) {
  int e = blockIdx.x * blockDim.x + threadIdx.x;
  if (e < E) atomicAdd(&deg[dst[e]], 1);
}

// dinv = rsqrt(deg + 1)  (+1 = self loop)
__global__ void k_dinv(const int* __restrict__ deg, float* __restrict__ dinv, int N) {
  int i = blockIdx.x * blockDim.x + threadIdx.x;
  if (i < N) dinv[i] = 1.0f / sqrtf((float)(deg[i] + 1));
}

// single-block exclusive scan of deg[0..N) -> row, cursor; row[N]=E
__global__ void k_scan(const int* __restrict__ deg, int* __restrict__ row,
                       int* __restrict__ cursor, int N, int E) {
  __shared__ int shW[16];
  __shared__ int s_carry;
  int tid = threadIdx.x, lane = tid & 63, w = tid >> 6;
  if (tid == 0) s_carry = 0;
  __syncthreads();
  for (int base = 0; base < N; base += 1024) {
    int i = base + tid;
    int v = (i < N) ? deg[i] : 0;
    int x = v;
#pragma unroll
    for (int off = 1; off < 64; off <<= 1) {
      int y = __shfl_up(x, off);
      if (lane >= off) x += y;
    }
    if (lane == 63) shW[w] = x;
    __syncthreads();
    int carry = s_carry;
    int wo = 0;
    for (int j = 0; j < w; ++j) wo += shW[j];
    int excl = carry + wo + x - v;
    if (i < N) { row[i] = excl; cursor[i] = excl; }
    int tot = 0;
    for (int j = 0; j < 16; ++j) tot += shW[j];
    __syncthreads();
    if (tid == 0) s_carry = carry + tot;
    __syncthreads();
  }
  if (tid == 0) row[N] = E;
}

// place edges into CSR (grouped by dst, storing src)
__global__ void k_place(const int* __restrict__ src, const int* __restrict__ dst, int E,
                        int* __restrict__ cursor, int* __restrict__ col) {
  int e = blockIdx.x * blockDim.x + threadIdx.x;
  if (e < E) {
    int d = dst[e];
    int p = atomicAdd(&cursor[d], 1);
    col[p] = src[e];
  }
}

// C[M,64] = A[M,K] @ W[K,64], K % 32 == 0. Block: 256 thr, 64 rows x 64 cols, 4x4 micro.
__global__ __launch_bounds__(256) void k_gemm64(const float* __restrict__ A,
                                                const float* __restrict__ W,
                                                float* __restrict__ C, int M, int K) {
  __shared__ float as[32][68];  // [k][m], padded, 16B-aligned rows
  __shared__ float bs[32][68];  // [k][n], padded
  int tid = threadIdx.x;
  int tx = tid & 15, ty = tid >> 4;
  int row0 = blockIdx.x * 64;
  float acc[4][4] = {};
  for (int k0 = 0; k0 < K; k0 += 32) {
    {
      int r = tid >> 2;            // 0..63
      int kk = (tid & 3) * 8;      // 0,8,16,24
      int grow = row0 + r;
      float4 v0 = make_float4(0.f, 0.f, 0.f, 0.f), v1 = v0;
      if (grow < M) {
        const float* srcp = A + (size_t)grow * K + k0 + kk;
        v0 = *(const float4*)(srcp);
        v1 = *(const float4*)(srcp + 4);
      }
      as[kk + 0][r] = v0.x; as[kk + 1][r] = v0.y; as[kk + 2][r] = v0.z; as[kk + 3][r] = v0.w;
      as[kk + 4][r] = v1.x; as[kk + 5][r] = v1.y; as[kk + 6][r] = v1.z; as[kk + 7][r] = v1.w;
    }
    {
      int kk = tid >> 3;           // 0..31
      int n = (tid & 7) * 8;
      const float* srcp = W + (size_t)(k0 + kk) * 64 + n;
      float4 v0 = *(const float4*)(srcp);
      float4 v1 = *(const float4*)(srcp + 4);
      *(float4*)&bs[kk][n] = v0;
      *(float4*)&bs[kk][n + 4] = v1;
    }
    __syncthreads();
#pragma unroll
    for (int kk = 0; kk < 32; ++kk) {
      float4 a = *(const float4*)&as[kk][ty * 4];
      float4 b = *(const float4*)&bs[kk][tx * 4];
      float av[4] = {a.x, a.y, a.z, a.w};
      float bv[4] = {b.x, b.y, b.z, b.w};
#pragma unroll
      for (int i = 0; i < 4; ++i)
#pragma unroll
        for (int j = 0; j < 4; ++j) acc[i][j] += av[i] * bv[j];
    }
    __syncthreads();
  }
  int r0 = row0 + ty * 4, c0 = tx * 4;
#pragma unroll
  for (int i = 0; i < 4; ++i) {
    int r = r0 + i;
    if (r < M)
      *(float4*)&C[(size_t)r * 64 + c0] =
          make_float4(acc[i][0], acc[i][1], acc[i][2], acc[i][3]);
  }
}

// out[i,:] = dinv[i]*( sum_{j in CSR(i)} dinv[j]*h[j,:] + dinv[i]*h[i,:] ) + bias
// one wave per row (4 waves/block)
__global__ void k_agg(const float* __restrict__ h, const int* __restrict__ row,
                      const int* __restrict__ col, const float* __restrict__ dinv,
                      const float* __restrict__ bias, float* __restrict__ out, int N) {
  int w = threadIdx.x >> 6;
  int lane = threadIdx.x & 63;
  int i = blockIdx.x * 4 + w;
  if (i >= N) return;
  float di = dinv[i];
  int s = row[i], e = row[i + 1];
  float acc = di * h[(size_t)i * 64 + lane];  // self-loop term (gets another di at the end)
  for (int base = s; base < e; base += 64) {
    int idx = base + lane;
    int cidx = (idx < e) ? col[idx] : 0;
    float dv = (idx < e) ? dinv[cidx] : 0.0f;
    int cnt = min(64, e - base);
    for (int t = 0; t < cnt; ++t) {
      int j = __shfl(cidx, t);
      float dj = __shfl(dv, t);
      acc += dj * h[(size_t)j * 64 + lane];
    }
  }
  out[(size_t)i * 64 + lane] = di * acc + bias[lane];
}

// fold link-predictor weights: Mp = Wproj[0:64,:]@Wl1, Ms = Wproj[64:128,:]@Wl1,
// cvec = bproj@Wl1 + bl1
__global__ void k_fold(const float* __restrict__ Wproj, const float* __restrict__ bproj,
                       const float* __restrict__ Wl1, const float* __restrict__ bl1,
                       float* __restrict__ Mp, float* __restrict__ Ms,
                       float* __restrict__ cvec) {
  int t = blockIdx.x * blockDim.x + threadIdx.x;
  if (t < 8192) {
    int which = t >> 12;
    int idx = t & 4095;
    int a = idx >> 6, c = idx & 63;
    const float* wrow = Wproj + (size_t)(which * 64 + a) * 128;
    float sum = 0.f;
    for (int k = 0; k < 128; ++k) sum += wrow[k] * Wl1[(size_t)k * 64 + c];
    (which ? Ms : Mp)[idx] = sum;
  } else if (t < 8256) {
    int c = t - 8192;
    float sum = bl1[c];
    for (int k = 0; k < 128; ++k) sum += bproj[k] * Wl1[(size_t)k * 64 + c];
    cvec[c] = sum;
  }
}

// out[e] = relu(P[ep[e],:] + S[es[e],:] + c) . wl2 + bl2   (16 lanes per edge)
__global__ void k_link(const float* __restrict__ P, const float* __restrict__ S,
                       const int* __restrict__ ep, const int* __restrict__ es,
                       const float* __restrict__ cvec, const float* __restrict__ wl2,
                       const float* __restrict__ bl2, float* __restrict__ out, int EL) {
  int lane = threadIdx.x & 63;
  int g = lane >> 4;   // edge slot within wave
  int f = lane & 15;   // feature quad index
  int wave = threadIdx.x >> 6;
  float4 c4 = *(const float4*)&cvec[f * 4];
  float4 w4 = *(const float4*)&wl2[f * 4];
  float b2 = bl2[0];
  int e0 = blockIdx.x * 16 + wave * 4 + g;
  int step = gridDim.x * 16;
  for (int e = e0; e < EL; e += step) {
    int rp = ep[e], rs = es[e];
    float4 p4 = *(const float4*)&P[(size_t)rp * 64 + f * 4];
    float4 s4 = *(const float4*)&S[(size_t)rs * 64 + f * 4];
    float u, acc;
    u = p4.x + s4.x + c4.x; acc  = fmaxf(u, 0.f) * w4.x;
    u = p4.y + s4.y + c4.y; acc += fmaxf(u, 0.f) * w4.y;
    u = p4.z + s4.z + c4.z; acc += fmaxf(u, 0.f) * w4.z;
    u = p4.w + s4.w + c4.w; acc += fmaxf(u, 0.f) * w4.w;
    acc += __shfl_xor(acc, 1);
    acc += __shfl_xor(acc, 2);
    acc += __shfl_xor(acc, 4);
    acc += __shfl_xor(acc, 8);
    if (f == 0) out[e] = acc + b2;
  }
}

extern "C" void kernel_launch(void* const* d_in, const int* in_sizes, int n_in,
                              void* d_out, int out_size, void* d_ws, size_t ws_size,
                              hipStream_t stream) {
  const float* x_p  = (const float*)d_in[0];
  const float* x_s  = (const float*)d_in[1];
  const int*   ei_p = (const int*)d_in[2];
  const int*   ei_s = (const int*)d_in[3];
  const int*   ed_p = (const int*)d_in[4];
  const int*   ed_s = (const int*)d_in[5];
  const float* Wp1 = (const float*)d_in[6];  const float* bp1 = (const float*)d_in[7];
  const float* Ws1 = (const float*)d_in[8];  const float* bs1 = (const float*)d_in[9];
  const float* Wp2 = (const float*)d_in[10]; const float* bp2 = (const float*)d_in[11];
  const float* Ws2 = (const float*)d_in[12]; const float* bs2 = (const float*)d_in[13];
  const float* Wproj = (const float*)d_in[14]; const float* bproj = (const float*)d_in[15];
  const float* Wl1 = (const float*)d_in[16]; const float* bl1 = (const float*)d_in[17];
  const float* Wl2 = (const float*)d_in[18]; const float* bl2 = (const float*)d_in[19];
  float* out = (float*)d_out;

  char* wsp = (char*)d_ws;
  size_t off = 0;
  auto alloc = [&](size_t b) -> void* {
    void* p = wsp + off;
    off = (off + b + 255) & ~(size_t)255;
    return p;
  };
  float* bufA_p = (float*)alloc((size_t)NPn * 64 * 4);
  float* bufB_p = (float*)alloc((size_t)NPn * 64 * 4);
  float* bufA_s = (float*)alloc((size_t)NSn * 64 * 4);
  float* bufB_s = (float*)alloc((size_t)NSn * 64 * 4);
  int*   col_p  = (int*)alloc((size_t)EPe * 4);
  int*   col_s  = (int*)alloc((size_t)ESe * 4);
  int*   deg_p  = (int*)alloc((size_t)NPn * 4);
  int*   deg_s  = (int*)alloc((size_t)NSn * 4);
  float* dinv_p = (float*)alloc((size_t)NPn * 4);
  float* dinv_s = (float*)alloc((size_t)NSn * 4);
  int*   row_p  = (int*)alloc((size_t)(NPn + 1) * 4);
  int*   row_s  = (int*)alloc((size_t)(NSn + 1) * 4);
  int*   cur_p  = (int*)alloc((size_t)NPn * 4);
  int*   cur_s  = (int*)alloc((size_t)NSn * 4);
  float* Mp     = (float*)alloc(64 * 64 * 4);
  float* Ms     = (float*)alloc(64 * 64 * 4);
  float* cvec   = (float*)alloc(64 * 4);
  (void)ws_size; (void)n_in; (void)in_sizes; (void)out_size;

  const int* src_p = ei_p;           const int* dst_p = ei_p + EPe;
  const int* src_s = ei_s;           const int* dst_s = ei_s + ESe;

  hipMemsetAsync(deg_p, 0, (size_t)NPn * 4, stream);
  hipMemsetAsync(deg_s, 0, (size_t)NSn * 4, stream);

  // weight folding (independent, launch early)
  k_fold<<<33, 256, 0, stream>>>(Wproj, bproj, Wl1, bl1, Mp, Ms, cvec);

  // degree + dinv + CSR
  k_deg<<<(EPe + 255) / 256, 256, 0, stream>>>(dst_p, EPe, deg_p);
  k_deg<<<(ESe + 255) / 256, 256, 0, stream>>>(dst_s, ESe, deg_s);
  k_dinv<<<(NPn + 255) / 256, 256, 0, stream>>>(deg_p, dinv_p, NPn);
  k_dinv<<<(NSn + 255) / 256, 256, 0, stream>>>(deg_s, dinv_s, NSn);
  k_scan<<<1, 1024, 0, stream>>>(deg_p, row_p, cur_p, NPn, EPe);
  k_scan<<<1, 1024, 0, stream>>>(deg_s, row_s, cur_s, NSn, ESe);
  k_place<<<(EPe + 255) / 256, 256, 0, stream>>>(src_p, dst_p, EPe, cur_p, col_p);
  k_place<<<(ESe + 255) / 256, 256, 0, stream>>>(src_s, dst_s, ESe, cur_s, col_s);

  // protein encoder
  k_gemm64<<<(NPn + 63) / 64, 256, 0, stream>>>(x_p, Wp1, bufA_p, NPn, PDk);
  k_agg<<<(NPn + 3) / 4, 256, 0, stream>>>(bufA_p, row_p, col_p, dinv_p, bp1, bufB_p, NPn);
  k_gemm64<<<(NPn + 63) / 64, 256, 0, stream>>>(bufB_p, Wp2, bufA_p, NPn, 64);
  k_agg<<<(NPn + 3) / 4, 256, 0, stream>>>(bufA_p, row_p, col_p, dinv_p, bp2, bufB_p, NPn);
  // P table = z_p @ Mp
  k_gemm64<<<(NPn + 63) / 64, 256, 0, stream>>>(bufB_p, Mp, bufA_p, NPn, 64);

  // substrate encoder
  k_gemm64<<<(NSn + 63) / 64, 256, 0, stream>>>(x_s, Ws1, bufA_s, NSn, SDk);
  k_agg<<<(NSn + 3) / 4, 256, 0, stream>>>(bufA_s, row_s, col_s, dinv_s, bs1, bufB_s, NSn);
  k_gemm64<<<(NSn + 63) / 64, 256, 0, stream>>>(bufB_s, Ws2, bufA_s, NSn, 64);
  k_agg<<<(NSn + 3) / 4, 256, 0, stream>>>(bufA_s, row_s, col_s, dinv_s, bs2, bufB_s, NSn);
  // S table = z_s @ Ms
  k_gemm64<<<(NSn + 63) / 64, 256, 0, stream>>>(bufB_s, Ms, bufA_s, NSn, 64);

  // link predictor
  k_link<<<(ELe + 15) / 16, 256, 0, stream>>>(bufA_p, bufA_s, ed_p, ed_s, cvec, Wl2,
                                              bl2, out, ELe);
}